// Round 2
// baseline (915.013 us; speedup 1.0000x reference)
//
#include <hip/hip_runtime.h>
#include <math.h>

typedef unsigned short u16;
typedef unsigned int u32;
typedef float f32x4 __attribute__((ext_vector_type(4)));
typedef __bf16 bf16x8 __attribute__((ext_vector_type(8)));

#define NTOK 16384      // B*S
#define HD   2048
#define KX   4096       // concat K
#define NW   2176       // padded N for gemm2 (2048 d + 16 a_t + 16 a_s + 96 pad)
#define NB   256        // Bcat rows (128 B_s + 128 B_t)

// ---------------- helpers ----------------
__device__ __forceinline__ u16 f2bf(float f) {
  u32 u = __float_as_uint(f);
  u32 r = (u + 0x7fffu + ((u >> 16) & 1u)) >> 16;   // RNE
  return (u16)r;
}
__device__ __forceinline__ float bf2f(u16 s) { return __uint_as_float(((u32)s) << 16); }

__device__ __forceinline__ void gload_lds16(const void* g, void* l) {
  __builtin_amdgcn_global_load_lds((const __attribute__((address_space(1))) u32*)g,
                                   (__attribute__((address_space(3))) u32*)l, 16, 0, 0);
}

// ---------------- tiny init kernels ----------------
__global__ void zero_accum_k(float* a) {
  if (threadIdx.x < 32) a[threadIdx.x] = 0.f;
}

__global__ void make_bias_k(const float* __restrict__ b_t, const float* __restrict__ b_s,
                            float* __restrict__ db) {
  int i = blockIdx.x * 256 + threadIdx.x;
  if (i < HD) db[i] = b_s[i] - b_t[i];
}

// ---------------- converts ----------------
__global__ __launch_bounds__(256) void convert_X_k(const float* __restrict__ th,
                                                   const float* __restrict__ sh,
                                                   u16* __restrict__ X) {
  size_t t = (size_t)blockIdx.x * 256 + threadIdx.x;   // 8,388,608 threads, 8 elems each
  int n = (int)(t >> 9);
  int k = ((int)t & 511) * 8;
  const float* src = (k < HD) ? (th + (size_t)n * HD + k) : (sh + (size_t)n * HD + (k - HD));
  float4 v0 = *(const float4*)src;
  float4 v1 = *(const float4*)(src + 4);
  uint4 pk;
  pk.x = (u32)f2bf(v0.x) | ((u32)f2bf(v0.y) << 16);
  pk.y = (u32)f2bf(v0.z) | ((u32)f2bf(v0.w) << 16);
  pk.z = (u32)f2bf(v1.x) | ((u32)f2bf(v1.y) << 16);
  pk.w = (u32)f2bf(v1.z) | ((u32)f2bf(v1.w) << 16);
  *(uint4*)(X + t * 8) = pk;
}

__global__ __launch_bounds__(256) void convert_W_k(const float* __restrict__ W_t,
                                                   const float* __restrict__ W_s,
                                                   const float* __restrict__ A_t,
                                                   const float* __restrict__ A_s,
                                                   u16* __restrict__ Wc) {
  size_t t = (size_t)blockIdx.x * 256 + threadIdx.x;   // 2176*512 threads
  int nr = (int)(t >> 9);
  int k = ((int)t & 511) * 8;
  float f[8];
#pragma unroll
  for (int j = 0; j < 8; ++j) f[j] = 0.f;
  if (nr < HD) {
    if (k < HD) {
      const float* s = W_t + (size_t)nr * HD + k;
#pragma unroll
      for (int j = 0; j < 8; ++j) f[j] = -s[j];
    } else {
      const float* s = W_s + (size_t)nr * HD + (k - HD);
#pragma unroll
      for (int j = 0; j < 8; ++j) f[j] = s[j];
    }
  } else if (nr < HD + 16) {          // A_t rows, active on k<2048
    if (k < HD) {
      const float* s = A_t + (size_t)(nr - HD) * HD + k;
#pragma unroll
      for (int j = 0; j < 8; ++j) f[j] = s[j];
    }
  } else if (nr < HD + 32) {          // A_s rows, active on k>=2048
    if (k >= HD) {
      const float* s = A_s + (size_t)(nr - HD - 16) * HD + (k - HD);
#pragma unroll
      for (int j = 0; j < 8; ++j) f[j] = s[j];
    }
  }
  uint4 pk;
  pk.x = (u32)f2bf(f[0]) | ((u32)f2bf(f[1]) << 16);
  pk.y = (u32)f2bf(f[2]) | ((u32)f2bf(f[3]) << 16);
  pk.z = (u32)f2bf(f[4]) | ((u32)f2bf(f[5]) << 16);
  pk.w = (u32)f2bf(f[6]) | ((u32)f2bf(f[7]) << 16);
  *(uint4*)(Wc + t * 8) = pk;
}

__global__ __launch_bounds__(256) void convert_Bc_k(const float* __restrict__ Bs_,
                                                    const float* __restrict__ Bt_,
                                                    u16* __restrict__ Bc) {
  size_t t = (size_t)blockIdx.x * 256 + threadIdx.x;   // 65536 threads, 8 elems each
  int c = (int)(t >> 8);           // 0..255
  int h = ((int)t & 255) * 8;
  const float* src = (c < 128) ? Bs_ : Bt_;
  int e = (c & 127) >> 4, r = c & 15;
  const float* base = src + (size_t)e * HD * 16 + (size_t)h * 16 + r;
  float f[8];
#pragma unroll
  for (int j = 0; j < 8; ++j) f[j] = base[(size_t)j * 16];
  uint4 pk;
  pk.x = (u32)f2bf(f[0]) | ((u32)f2bf(f[1]) << 16);
  pk.y = (u32)f2bf(f[2]) | ((u32)f2bf(f[3]) << 16);
  pk.z = (u32)f2bf(f[4]) | ((u32)f2bf(f[5]) << 16);
  pk.w = (u32)f2bf(f[6]) | ((u32)f2bf(f[7]) << 16);
  *(uint4*)(Bc + t * 8) = pk;
}

// ---------------- Gram matrices  G[e][r][q] (f32) ----------------
__global__ __launch_bounds__(256) void gram_k(const float* __restrict__ Bs_,
                                              const float* __restrict__ Bt_,
                                              float* __restrict__ grams) {
  __shared__ float ss[128 * 16];
  __shared__ float st[128 * 16];
  const int e = blockIdx.x;
  const int tid = threadIdx.x;
  const float* bs = Bs_ + (size_t)e * HD * 16;
  const float* bt = Bt_ + (size_t)e * HD * 16;
  const int r = tid >> 4, q = tid & 15;
  float gss = 0.f, gst = 0.f, gtt = 0.f;
  for (int h0 = 0; h0 < HD; h0 += 128) {
    __syncthreads();
#pragma unroll
    for (int j = 0; j < 8; ++j) {
      int i = tid + j * 256;
      ss[i] = bs[(size_t)h0 * 16 + i];
      st[i] = bt[(size_t)h0 * 16 + i];
    }
    __syncthreads();
    for (int hh = 0; hh < 128; ++hh) {
      float vsr = ss[hh * 16 + r], vsq = ss[hh * 16 + q];
      float vtr = st[hh * 16 + r], vtq = st[hh * 16 + q];
      gss += vsr * vsq;
      gst += vsr * vtq;   // G_st[r][q] = sum_h Bs[h,r] * Bt[h,q]
      gtt += vtr * vtq;
    }
  }
  grams[e * 256 + r * 16 + q] = gss;
  grams[2048 + e * 256 + r * 16 + q] = gst;
  grams[4096 + e * 256 + r * 16 + q] = gtt;
}

// ---------------- 128x128 MFMA GEMM (C[m,n] = sum_k A[m,k]*Bm[n,k]) ----------------
template <bool OUT_BF16>
__global__ __launch_bounds__(256) void gemm_bt_k(const u16* __restrict__ A, int lda,
                                                 const u16* __restrict__ Bm, int ldb,
                                                 int K, void* __restrict__ Cp, int ldc,
                                                 const float* __restrict__ bias, int bias_n) {
  __shared__ u16 As[128 * 32];
  __shared__ u16 Bs[128 * 32];
  const int tid = threadIdx.x;
  const int wave = tid >> 6;
  const int lane = tid & 63;
  const int m0 = blockIdx.x * 128;
  const int n0 = blockIdx.y * 128;
  const int wm = (wave >> 1) * 64;
  const int wn = (wave & 1) * 64;
  f32x4 acc[4][4] = {};

  const int srow = wave * 32 + (lane >> 2);   // this wave's seg0 row
  const int scol = (lane & 3) * 8;
  const u16* gA = A + (size_t)(m0 + srow) * lda + scol;
  const u16* gB = Bm + (size_t)(n0 + srow) * ldb + scol;
  u16* lA = As + wave * 1024;
  u16* lB = Bs + wave * 1024;

  for (int k0 = 0; k0 < K; k0 += 32) {
    gload_lds16(gA + k0, lA);
    gload_lds16(gA + k0 + (size_t)16 * lda, lA + 512);
    gload_lds16(gB + k0, lB);
    gload_lds16(gB + k0 + (size_t)16 * ldb, lB + 512);
    __syncthreads();
    bf16x8 af[4], bff[4];
#pragma unroll
    for (int mi = 0; mi < 4; ++mi)
      af[mi] = *(const bf16x8*)&As[(wm + mi * 16 + (lane & 15)) * 32 + (lane >> 4) * 8];
#pragma unroll
    for (int ni = 0; ni < 4; ++ni)
      bff[ni] = *(const bf16x8*)&Bs[(wn + ni * 16 + (lane & 15)) * 32 + (lane >> 4) * 8];
#pragma unroll
    for (int mi = 0; mi < 4; ++mi)
#pragma unroll
      for (int ni = 0; ni < 4; ++ni)
        acc[mi][ni] = __builtin_amdgcn_mfma_f32_16x16x32_bf16(af[mi], bff[ni], acc[mi][ni], 0, 0, 0);
    __syncthreads();
  }

#pragma unroll
  for (int mi = 0; mi < 4; ++mi) {
#pragma unroll
    for (int ni = 0; ni < 4; ++ni) {
      int row0 = m0 + wm + mi * 16 + (lane >> 4) * 4;
      int col = n0 + wn + ni * 16 + (lane & 15);
      float badd = 0.f;
      if (bias != nullptr && col < bias_n) badd = bias[col];
      f32x4 v = acc[mi][ni];
#pragma unroll
      for (int j = 0; j < 4; ++j) {
        float x = v[j] + badd;
        if (OUT_BF16)
          ((u16*)Cp)[(size_t)(row0 + j) * ldc + col] = f2bf(x);
        else
          ((float*)Cp)[(size_t)(row0 + j) * ldc + col] = x;
      }
    }
  }
}

// ---------------- per-token kernel: mse assembly + MC scan + method B ----------------
__global__ __launch_bounds__(256) void token_k(const u16* __restrict__ D,
                                               const float* __restrict__ proj,
                                               const float* __restrict__ grams,
                                               const float* __restrict__ tg,
                                               const float* __restrict__ sg,
                                               const float* __restrict__ un,
                                               const int* __restrict__ maskp,
                                               const float* __restrict__ temp,
                                               float* __restrict__ accum) {
  __shared__ float blk[20];
  if (threadIdx.x < 20) blk[threadIdx.x] = 0.f;
  __syncthreads();
  const int wave = threadIdx.x >> 6, lane = threadIdx.x & 63;
  const int n = blockIdx.x * 4 + wave;
  const u16* drow = D + (size_t)n * NW;

  // ---- mean_base = mean_h d^2 ----
  float ssum = 0.f;
#pragma unroll
  for (int j = 0; j < 4; ++j) {
    uint4 v = *(const uint4*)(drow + j * 512 + lane * 8);
    u32 w;
    float f;
    w = v.x; f = bf2f((u16)(w & 0xffff)); ssum += f * f; f = bf2f((u16)(w >> 16)); ssum += f * f;
    w = v.y; f = bf2f((u16)(w & 0xffff)); ssum += f * f; f = bf2f((u16)(w >> 16)); ssum += f * f;
    w = v.z; f = bf2f((u16)(w & 0xffff)); ssum += f * f; f = bf2f((u16)(w >> 16)); ssum += f * f;
    w = v.w; f = bf2f((u16)(w & 0xffff)); ssum += f * f; f = bf2f((u16)(w >> 16)); ssum += f * f;
  }
#pragma unroll
  for (int m = 1; m < 64; m <<= 1) ssum += __shfl_xor(ssum, m);
  const float mean_base = ssum * (1.0f / (float)HD);

  // ---- a vectors (static-index-only register arrays) ----
  float a_tv[16], a_sv[16];
#pragma unroll
  for (int r = 0; r < 16; ++r) {
    a_tv[r] = bf2f(drow[HD + r]);
    a_sv[r] = bf2f(drow[HD + 16 + r]);
  }

  // ---- cross + quad partials: lane handles expert e = lane&7, rows {2p,2p+1} ----
  const int e = lane & 7;
  const int pp = lane >> 3;
  const float* Ps = proj + (size_t)n * 256 + e * 16;
  const float* Pt = Ps + 128;
  const float* Gss = grams + e * 256;
  const float* Gst = grams + 2048 + e * 256;
  const float* Gtt = grams + 4096 + e * 256;
  float crossp = 0.f, qss = 0.f, qst = 0.f, qtt = 0.f;
#pragma unroll
  for (int rr = 0; rr < 2; ++rr) {
    int r = pp * 2 + rr;
    float asr = bf2f(drow[HD + 16 + r]);   // runtime r -> direct load, not reg array
    float atr = bf2f(drow[HD + r]);
    crossp += 2.0f * Ps[r] * asr - 2.0f * Pt[r] * atr;   // SCALE_S = SCALE_T = 2
    const float* gssr = Gss + r * 16;
    const float* gstr = Gst + r * 16;
    const float* gttr = Gtt + r * 16;
    float vss = 0.f, vst = 0.f, vtt = 0.f;
#pragma unroll
    for (int q = 0; q < 16; ++q) {
      vss += gssr[q] * a_sv[q];
      vst += gstr[q] * a_tv[q];
      vtt += gttr[q] * a_tv[q];
    }
    qss += asr * vss;
    qst += asr * vst;
    qtt += atr * vtt;
  }
#pragma unroll
  for (int m = 8; m < 64; m <<= 1) {
    crossp += __shfl_xor(crossp, m);
    qss += __shfl_xor(qss, m);
    qst += __shfl_xor(qst, m);
    qtt += __shfl_xor(qtt, m);
  }
  float quad = 4.0f * qss - 8.0f * qst + 4.0f * qtt;   // S^2, 2*Ss*St, T^2 with scales=2
  float my_mse = mean_base + (2.0f / (float)HD) * crossp + (1.0f / (float)HD) * quad;
  // lanes 0..7 hold mse for experts 0..7

  // ---- method A: K=3 MC scan with alpha-renorm (all lanes redundant) ----
  float p[8], gt[8], gs[8];
#pragma unroll
  for (int i = 0; i < 8; ++i) {
    gt[i] = tg[(size_t)n * 8 + i];
    gs[i] = sg[(size_t)n * 8 + i];
    p[i] = gt[i];
  }
  const float mf = (float)maskp[n];
  float feat = 0.f, wsum = 0.f;
  float tc[8] = {0, 0, 0, 0, 0, 0, 0, 0};
  float sc[8] = {0, 0, 0, 0, 0, 0, 0, 0};
#pragma unroll
  for (int k = 0; k < 3; ++k) {
    int idx = 0;
    float best = -1e30f;
#pragma unroll
    for (int i = 0; i < 8; ++i) {
      float u = un[((size_t)k * NTOK + n) * 8 + i];
      float g = -logf(-logf(u * (1.0f - 2e-7f) + 1e-7f));
      float s = logf(p[i]) + g;
      if (s > best) { best = s; idx = i; }
    }
    float w = 0.f, sgi = 0.f;
#pragma unroll
    for (int i = 0; i < 8; ++i)
      if (i == idx) { w = p[i]; sgi = gs[i]; }
    float mse_k = __shfl(my_mse, idx);
    feat += mf * w * mse_k;
    wsum += mf * w;
#pragma unroll
    for (int i = 0; i < 8; ++i)
      if (i == idx) { tc[i] += mf * w; sc[i] += mf * sgi; }
    float sum = 0.f;
#pragma unroll
    for (int i = 0; i < 8; ++i) {
      if (i == idx) p[i] *= 0.5f;   // ALPHA = 0.5
      sum += p[i];
    }
#pragma unroll
    for (int i = 0; i < 8; ++i) p[i] /= sum;
  }

  // ---- method B: temp-softmax KL + entropy ----
  float tcl = fminf(fmaxf(temp[0], 0.5f), 1.5f);
  float invt = 1.0f / tcl;
  float x[8];
  float xm = -1e30f;
#pragma unroll
  for (int i = 0; i < 8; ++i) { x[i] = gs[i] * invt; xm = fmaxf(xm, x[i]); }
  float sx = 0.f;
#pragma unroll
  for (int i = 0; i < 8; ++i) sx += expf(x[i] - xm);
  float lse = xm + logf(sx);
  float tkl = 0.f, ent = 0.f;
#pragma unroll
  for (int i = 0; i < 8; ++i) {
    tkl += gt[i] * (logf(gt[i]) - (x[i] - lse));
    ent -= gs[i] * logf(gs[i]);
  }

  // ---- block reduce ----
  if (lane == 0) {
    atomicAdd(&blk[0], feat);
    atomicAdd(&blk[1], wsum);
#pragma unroll
    for (int i = 0; i < 8; ++i) {
      atomicAdd(&blk[2 + i], tc[i]);
      atomicAdd(&blk[10 + i], sc[i]);
    }
    atomicAdd(&blk[18], tkl);
    atomicAdd(&blk[19], ent);
  }
  __syncthreads();
  if (threadIdx.x < 20) atomicAdd(&accum[threadIdx.x], blk[threadIdx.x]);
}

// ---------------- finalize ----------------
__global__ void finalize_k(const float* __restrict__ accum, const float* __restrict__ temp,
                           float* __restrict__ out) {
  if (threadIdx.x != 0 || blockIdx.x != 0) return;
  float feat = accum[0] / fmaxf(accum[1], 1e-8f);
  float tsum = 0.f, ssum = 0.f;
  for (int e2 = 0; e2 < 8; ++e2) { tsum += accum[2 + e2]; ssum += accum[10 + e2]; }
  float ta[8], sa[8];
  float tas = 0.f, sas = 0.f;
  for (int e2 = 0; e2 < 8; ++e2) {
    ta[e2] = accum[2 + e2] / tsum + 1e-8f; tas += ta[e2];
    sa[e2] = accum[10 + e2] / ssum + 1e-8f; sas += sa[e2];
  }
  float cov = 0.f;
  for (int e2 = 0; e2 < 8; ++e2) {
    float tt = ta[e2] / tas, sv = sa[e2] / sas;
    cov += tt * (logf(tt) - logf(sv));
  }
  cov /= 8.0f;
  float tcl = fminf(fmaxf(temp[0], 0.5f), 1.5f);
  float tkl = accum[18] / 8.0f;            // divide by B
  float entl = -accum[19] / (float)NTOK;   // -mean(entropy)
  out[0] = feat;
  out[1] = cov;
  out[2] = feat + 0.5f * cov;
  out[3] = tkl;
  out[4] = entl;
  out[5] = tkl + 0.1f * entl;
  out[6] = tcl;
}

// ---------------- launch ----------------
extern "C" void kernel_launch(void* const* d_in, const int* in_sizes, int n_in,
                              void* d_out, int out_size, void* d_ws, size_t ws_size,
                              hipStream_t stream) {
  const float* tg = (const float*)d_in[0];
  const float* sg = (const float*)d_in[1];
  const float* th = (const float*)d_in[2];
  const float* sh = (const float*)d_in[3];
  const int* mask = (const int*)d_in[4];
  const float* un = (const float*)d_in[5];
  const float* W_t = (const float*)d_in[6];
  const float* b_t = (const float*)d_in[7];
  const float* A_t = (const float*)d_in[8];
  const float* B_t = (const float*)d_in[9];
  const float* W_s = (const float*)d_in[10];
  const float* b_s = (const float*)d_in[11];
  const float* A_s = (const float*)d_in[12];
  const float* B_s = (const float*)d_in[13];
  const float* temp = (const float*)d_in[14];
  float* out = (float*)d_out;

  char* ws = (char*)d_ws;
  const size_t OFF_X = 0;                              // 16384*4096*2   = 134217728
  const size_t OFF_W = OFF_X + (size_t)NTOK * KX * 2;  // 2176*4096*2    = 17825792
  const size_t OFF_D = OFF_W + (size_t)NW * KX * 2;    // 16384*2176*2   = 71303168
  const size_t OFF_BC = OFF_D + (size_t)NTOK * NW * 2; // 256*2048*2     = 1048576
  const size_t OFF_PJ = OFF_BC + (size_t)NB * HD * 2;  // 16384*256*4    = 16777216
  const size_t OFF_GR = OFF_PJ + (size_t)NTOK * 256 * 4; // 3*8*256*4    = 24576
  const size_t OFF_AC = OFF_GR + 6144 * 4;             // 32*4
  const size_t OFF_BI = OFF_AC + 128;                  // 2048*4

  u16* X = (u16*)(ws + OFF_X);
  u16* Wc = (u16*)(ws + OFF_W);
  u16* D = (u16*)(ws + OFF_D);
  u16* Bc = (u16*)(ws + OFF_BC);
  float* proj = (float*)(ws + OFF_PJ);
  float* grams = (float*)(ws + OFF_GR);
  float* accum = (float*)(ws + OFF_AC);
  float* dbias = (float*)(ws + OFF_BI);

  zero_accum_k<<<1, 64, 0, stream>>>(accum);
  make_bias_k<<<8, 256, 0, stream>>>(b_t, b_s, dbias);
  convert_X_k<<<32768, 256, 0, stream>>>(th, sh, X);
  convert_W_k<<<4352, 256, 0, stream>>>(W_t, W_s, A_t, A_s, Wc);
  convert_Bc_k<<<256, 256, 0, stream>>>(B_s, B_t, Bc);
  gram_k<<<8, 256, 0, stream>>>(B_s, B_t, grams);

  // d (+bias) and a_t/a_s columns, bf16 out: [16384][2176]
  gemm_bt_k<true><<<dim3(128, 17), 256, 0, stream>>>(X, KX, Wc, KX, KX, (void*)D, NW, dbias, HD);
  // proj = d @ [B_s|B_t]: f32 out [16384][256]
  gemm_bt_k<false><<<dim3(128, 2), 256, 0, stream>>>(D, NW, Bc, HD, HD, (void*)proj, 256, nullptr, 0);

  token_k<<<4096, 256, 0, stream>>>(D, proj, grams, tg, sg, un, mask, temp, accum);
  finalize_k<<<1, 64, 0, stream>>>(accum, temp, out);
}

// Round 4
// 864.925 us; speedup vs baseline: 1.0579x; 1.0579x over previous
//
#include <hip/hip_runtime.h>
#include <math.h>

typedef unsigned short u16;
typedef unsigned int u32;
typedef float f32x4 __attribute__((ext_vector_type(4)));
typedef __bf16 bf16x8 __attribute__((ext_vector_type(8)));

#define NTOK 16384      // B*S
#define HD   2048
#define KX   4096       // concat K (th|sh)

// ---------------- helpers ----------------
__device__ __forceinline__ u16 f2bf(float f) {
  u32 u = __float_as_uint(f);
  u32 r = (u + 0x7fffu + ((u >> 16) & 1u)) >> 16;   // RNE
  return (u16)r;
}
__device__ __forceinline__ float bf2f(u16 s) { return __uint_as_float(((u32)s) << 16); }

__device__ __forceinline__ void gload_lds16(const void* g, void* l) {
  __builtin_amdgcn_global_load_lds((const __attribute__((address_space(1))) u32*)g,
                                   (__attribute__((address_space(3))) u32*)l, 16, 0, 0);
}

// ---------------- tiny init kernels ----------------
__global__ void zero_k(float* a, int n) {
  int i = blockIdx.x * 256 + threadIdx.x;
  if (i < n) a[i] = 0.f;
}

__global__ void make_bias_k(const float* __restrict__ b_t, const float* __restrict__ b_s,
                            float* __restrict__ db) {
  int i = blockIdx.x * 256 + threadIdx.x;
  if (i < HD) db[i] = b_s[i] - b_t[i];
}

// ---------------- converts ----------------
__global__ __launch_bounds__(256) void convert_X_k(const float* __restrict__ th,
                                                   const float* __restrict__ sh,
                                                   u16* __restrict__ X) {
  size_t t = (size_t)blockIdx.x * 256 + threadIdx.x;   // 8,388,608 threads, 8 elems each
  int n = (int)(t >> 9);
  int k = ((int)t & 511) * 8;
  const float* src = (k < HD) ? (th + (size_t)n * HD + k) : (sh + (size_t)n * HD + (k - HD));
  float4 v0 = *(const float4*)src;
  float4 v1 = *(const float4*)(src + 4);
  uint4 pk;
  pk.x = (u32)f2bf(v0.x) | ((u32)f2bf(v0.y) << 16);
  pk.y = (u32)f2bf(v0.z) | ((u32)f2bf(v0.w) << 16);
  pk.z = (u32)f2bf(v1.x) | ((u32)f2bf(v1.y) << 16);
  pk.w = (u32)f2bf(v1.z) | ((u32)f2bf(v1.w) << 16);
  *(uint4*)(X + t * 8) = pk;
}

// Wc [2048][4096] = [-W_t | W_s]; WcA [128][4096] = rows 0-15 [A_t|0], 16-31 [0|A_s], rest 0
__global__ __launch_bounds__(256) void convert_W_k(const float* __restrict__ W_t,
                                                   const float* __restrict__ W_s,
                                                   const float* __restrict__ A_t,
                                                   const float* __restrict__ A_s,
                                                   u16* __restrict__ Wc,
                                                   u16* __restrict__ WcA) {
  size_t t = (size_t)blockIdx.x * 256 + threadIdx.x;   // 2176*512 threads
  int nr = (int)(t >> 9);
  int k = ((int)t & 511) * 8;
  float f[8];
#pragma unroll
  for (int j = 0; j < 8; ++j) f[j] = 0.f;
  u16* dst;
  if (nr < HD) {
    dst = Wc + (size_t)nr * KX + k;
    if (k < HD) {
      const float* s = W_t + (size_t)nr * HD + k;
#pragma unroll
      for (int j = 0; j < 8; ++j) f[j] = -s[j];
    } else {
      const float* s = W_s + (size_t)nr * HD + (k - HD);
#pragma unroll
      for (int j = 0; j < 8; ++j) f[j] = s[j];
    }
  } else {
    int nr2 = nr - HD;                       // 0..127
    dst = WcA + (size_t)nr2 * KX + k;
    if (nr2 < 16) {                          // A_t rows, active on k<2048
      if (k < HD) {
        const float* s = A_t + (size_t)nr2 * HD + k;
#pragma unroll
        for (int j = 0; j < 8; ++j) f[j] = s[j];
      }
    } else if (nr2 < 32) {                   // A_s rows, active on k>=2048
      if (k >= HD) {
        const float* s = A_s + (size_t)(nr2 - 16) * HD + (k - HD);
#pragma unroll
        for (int j = 0; j < 8; ++j) f[j] = s[j];
      }
    }
  }
  uint4 pk;
  pk.x = (u32)f2bf(f[0]) | ((u32)f2bf(f[1]) << 16);
  pk.y = (u32)f2bf(f[2]) | ((u32)f2bf(f[3]) << 16);
  pk.z = (u32)f2bf(f[4]) | ((u32)f2bf(f[5]) << 16);
  pk.w = (u32)f2bf(f[6]) | ((u32)f2bf(f[7]) << 16);
  *(uint4*)dst = pk;
}

__global__ __launch_bounds__(256) void convert_Bc_k(const float* __restrict__ Bs_,
                                                    const float* __restrict__ Bt_,
                                                    u16* __restrict__ Bc) {
  size_t t = (size_t)blockIdx.x * 256 + threadIdx.x;   // 65536 threads, 8 elems each
  int c = (int)(t >> 8);           // 0..255
  int h = ((int)t & 255) * 8;
  const float* src = (c < 128) ? Bs_ : Bt_;
  int e = (c & 127) >> 4, r = c & 15;
  const float* base = src + (size_t)e * HD * 16 + (size_t)h * 16 + r;
  float f[8];
#pragma unroll
  for (int j = 0; j < 8; ++j) f[j] = base[(size_t)j * 16];
  uint4 pk;
  pk.x = (u32)f2bf(f[0]) | ((u32)f2bf(f[1]) << 16);
  pk.y = (u32)f2bf(f[2]) | ((u32)f2bf(f[3]) << 16);
  pk.z = (u32)f2bf(f[4]) | ((u32)f2bf(f[5]) << 16);
  pk.w = (u32)f2bf(f[6]) | ((u32)f2bf(f[7]) << 16);
  *(uint4*)(Bc + t * 8) = pk;
}

// ---------------- Gram matrices G[e][r][q] (f32, atomic partials over 16 h-chunks) ----------------
__global__ __launch_bounds__(256) void gram_k(const float* __restrict__ Bs_,
                                              const float* __restrict__ Bt_,
                                              float* __restrict__ grams) {
  __shared__ float ss[128 * 16];
  __shared__ float st[128 * 16];
  const int e = blockIdx.x >> 4;
  const int ch = blockIdx.x & 15;
  const int tid = threadIdx.x;
  const float* bs = Bs_ + (size_t)e * HD * 16 + (size_t)ch * 128 * 16;
  const float* bt = Bt_ + (size_t)e * HD * 16 + (size_t)ch * 128 * 16;
#pragma unroll
  for (int j = 0; j < 8; ++j) {
    int i = tid + j * 256;
    ss[i] = bs[i];
    st[i] = bt[i];
  }
  __syncthreads();
  const int r = tid >> 4, q = tid & 15;
  float gss = 0.f, gst = 0.f, gtt = 0.f;
  for (int hh = 0; hh < 128; ++hh) {
    float vsr = ss[hh * 16 + r], vsq = ss[hh * 16 + q];
    float vtr = st[hh * 16 + r], vtq = st[hh * 16 + q];
    gss += vsr * vsq;
    gst += vsr * vtq;   // G_st[r][q] = sum_h Bs[h,r] * Bt[h,q]
    gtt += vtr * vtq;
  }
  atomicAdd(&grams[e * 256 + r * 16 + q], gss);
  atomicAdd(&grams[2048 + e * 256 + r * 16 + q], gst);
  atomicAdd(&grams[4096 + e * 256 + r * 16 + q], gtt);
}

// ---------------- 256x256 BK=64 single-barrier-per-tile MFMA GEMM ----------------
// D[m,n] = sum_k X[m,k]*Wc[n,k] + dbias[n], bf16 out.  M=16384, N=2048, K=4096.
__global__ __launch_bounds__(512, 2) void gemm256_k(const u16* __restrict__ A,
                                                    const u16* __restrict__ Bm,
                                                    u16* __restrict__ D,
                                                    const float* __restrict__ bias) {
  __shared__ u16 As[2][16384];   // [buf][256 rows x 64 cols], XOR-swizzled slots
  __shared__ u16 Bs[2][16384];
  const int tid = threadIdx.x;
  const int w = tid >> 6, l = tid & 63;
  // XCD mapping: block id%8 = XCD; each XCD owns one 256-col tile (Wc panel L2-resident)
  const int id = blockIdx.x;
  const int tile = (id & 7) * 64 + (id >> 3);
  const int m0 = (tile & 63) * 256;
  const int n0 = (tile >> 6) * 256;
  const int wm = (w >> 2) * 128;
  const int wn = (w & 3) * 64;

  f32x4 acc[8][4] = {};

  // staging: per tile, each thread issues 4 A + 4 B gload_lds16.
  // LDS dest linear; global source col pre-swizzled (slot ^= row&7) so swizzled reads are correct.
  const int rlo = w * 8 + (l >> 3);                 // row within 64-row group (i adds i*64)
  const int csw = ((l & 7) ^ (l >> 3)) * 8;         // inverse-swizzled col (elems)
  const u16* gA = A + (size_t)(m0 + rlo) * KX + csw;
  const u16* gB = Bm + (size_t)(n0 + rlo) * KX + csw;

  for (int t = 0; t < 64; ++t) {
    const int b = t & 1;
    if (t == 0) {
#pragma unroll
      for (int i = 0; i < 4; ++i) {
        gload_lds16(gA + (size_t)i * 64 * KX, &As[0][i * 4096 + w * 512]);
        gload_lds16(gB + (size_t)i * 64 * KX, &Bs[0][i * 4096 + w * 512]);
      }
    }
    // barrier: (a) waits this wave's tile-t loads (issued one full tile ago -> free drain),
    // (b) orders all reads of buf[b^1] (tile t-1) before the overwrite below.
    __syncthreads();
    if (t < 63) {
      const u16* ga = gA + (size_t)(t + 1) * 64;
      const u16* gb = gB + (size_t)(t + 1) * 64;
#pragma unroll
      for (int i = 0; i < 4; ++i) {
        gload_lds16(ga + (size_t)i * 64 * KX, &As[b ^ 1][i * 4096 + w * 512]);
        gload_lds16(gb + (size_t)i * 64 * KX, &Bs[b ^ 1][i * 4096 + w * 512]);
      }
    }
    // compute tile t from buf b: 2 ksub x 2 qm phases, no intra-tile barriers
#pragma unroll
    for (int ks = 0; ks < 2; ++ks) {
      bf16x8 bfr[4], afr[4];
#pragma unroll
      for (int n = 0; n < 4; ++n) {
        int row = wn + n * 16 + (l & 15);
        int off = (row * 64 + ks * 32 + (l >> 4) * 8) ^ ((row & 7) * 8);
        bfr[n] = *(const bf16x8*)&Bs[b][off];
      }
#pragma unroll
      for (int mm = 0; mm < 4; ++mm) {
        int row = wm + mm * 16 + (l & 15);
        int off = (row * 64 + ks * 32 + (l >> 4) * 8) ^ ((row & 7) * 8);
        afr[mm] = *(const bf16x8*)&As[b][off];
      }
      __builtin_amdgcn_s_setprio(1);
#pragma unroll
      for (int mm = 0; mm < 4; ++mm)
#pragma unroll
        for (int n = 0; n < 4; ++n)
          acc[mm][n] = __builtin_amdgcn_mfma_f32_16x16x32_bf16(afr[mm], bfr[n], acc[mm][n], 0, 0, 0);
      __builtin_amdgcn_s_setprio(0);
#pragma unroll
      for (int mm = 0; mm < 4; ++mm) {
        int row = wm + 64 + mm * 16 + (l & 15);
        int off = (row * 64 + ks * 32 + (l >> 4) * 8) ^ ((row & 7) * 8);
        afr[mm] = *(const bf16x8*)&As[b][off];
      }
      __builtin_amdgcn_s_setprio(1);
#pragma unroll
      for (int mm = 0; mm < 4; ++mm)
#pragma unroll
        for (int n = 0; n < 4; ++n)
          acc[4 + mm][n] = __builtin_amdgcn_mfma_f32_16x16x32_bf16(afr[mm], bfr[n], acc[4 + mm][n], 0, 0, 0);
      __builtin_amdgcn_s_setprio(0);
    }
  }

#pragma unroll
  for (int mi = 0; mi < 8; ++mi) {
#pragma unroll
    for (int ni = 0; ni < 4; ++ni) {
      int row0 = m0 + wm + mi * 16 + (l >> 4) * 4;
      int col = n0 + wn + ni * 16 + (l & 15);
      float badd = bias[col];
      f32x4 v = acc[mi][ni];
#pragma unroll
      for (int j = 0; j < 4; ++j)
        D[(size_t)(row0 + j) * HD + col] = f2bf(v[j] + badd);
    }
  }
}

// ---------------- 128x128 MFMA GEMM (C[m,n] = sum_k A[m,k]*Bm[n,k]) for proj + aV ----------------
__global__ __launch_bounds__(256) void gemm_bt_k(const u16* __restrict__ A, int lda,
                                                 const u16* __restrict__ Bm, int ldb,
                                                 int K, float* __restrict__ Cp, int ldc,
                                                 int store_n) {
  __shared__ u16 Asl[128 * 32];
  __shared__ u16 Bsl[128 * 32];
  const int tid = threadIdx.x;
  const int wave = tid >> 6;
  const int lane = tid & 63;
  const int m0 = blockIdx.x * 128;
  const int n0 = blockIdx.y * 128;
  const int wm = (wave >> 1) * 64;
  const int wn = (wave & 1) * 64;
  f32x4 acc[4][4] = {};

  const int srow = wave * 32 + (lane >> 2);
  const int scol = (lane & 3) * 8;
  const u16* gA = A + (size_t)(m0 + srow) * lda + scol;
  const u16* gB = Bm + (size_t)(n0 + srow) * ldb + scol;
  u16* lA = Asl + wave * 1024;
  u16* lB = Bsl + wave * 1024;

  for (int k0 = 0; k0 < K; k0 += 32) {
    gload_lds16(gA + k0, lA);
    gload_lds16(gA + k0 + (size_t)16 * lda, lA + 512);
    gload_lds16(gB + k0, lB);
    gload_lds16(gB + k0 + (size_t)16 * ldb, lB + 512);
    __syncthreads();
    bf16x8 af[4], bff[4];
#pragma unroll
    for (int mi = 0; mi < 4; ++mi)
      af[mi] = *(const bf16x8*)&Asl[(wm + mi * 16 + (lane & 15)) * 32 + (lane >> 4) * 8];
#pragma unroll
    for (int ni = 0; ni < 4; ++ni)
      bff[ni] = *(const bf16x8*)&Bsl[(wn + ni * 16 + (lane & 15)) * 32 + (lane >> 4) * 8];
#pragma unroll
    for (int mi = 0; mi < 4; ++mi)
#pragma unroll
      for (int ni = 0; ni < 4; ++ni)
        acc[mi][ni] = __builtin_amdgcn_mfma_f32_16x16x32_bf16(af[mi], bff[ni], acc[mi][ni], 0, 0, 0);
    __syncthreads();
  }

#pragma unroll
  for (int mi = 0; mi < 4; ++mi) {
#pragma unroll
    for (int ni = 0; ni < 4; ++ni) {
      int row0 = m0 + wm + mi * 16 + (lane >> 4) * 4;
      int col = n0 + wn + ni * 16 + (lane & 15);
      if (col < store_n) {
        f32x4 v = acc[mi][ni];
#pragma unroll
        for (int j = 0; j < 4; ++j)
          Cp[(size_t)(row0 + j) * ldc + col] = v[j];
      }
    }
  }
}

// ---------------- per-token kernel: mse assembly + MC scan + method B ----------------
__global__ __launch_bounds__(256) void token_k(const u16* __restrict__ D,
                                               const float* __restrict__ aV,
                                               const float* __restrict__ proj,
                                               const float* __restrict__ grams,
                                               const float* __restrict__ tg,
                                               const float* __restrict__ sg,
                                               const float* __restrict__ un,
                                               const int* __restrict__ maskp,
                                               const float* __restrict__ temp,
                                               float* __restrict__ accum) {
  __shared__ float blk[20];
  if (threadIdx.x < 20) blk[threadIdx.x] = 0.f;
  __syncthreads();
  const int wave = threadIdx.x >> 6, lane = threadIdx.x & 63;
  const int n = blockIdx.x * 4 + wave;
  const u16* drow = D + (size_t)n * HD;

  // ---- mean_base = mean_h d^2 ----
  float ssum = 0.f;
#pragma unroll
  for (int j = 0; j < 4; ++j) {
    uint4 v = *(const uint4*)(drow + j * 512 + lane * 8);
    u32 wv;
    float f;
    wv = v.x; f = bf2f((u16)(wv & 0xffff)); ssum += f * f; f = bf2f((u16)(wv >> 16)); ssum += f * f;
    wv = v.y; f = bf2f((u16)(wv & 0xffff)); ssum += f * f; f = bf2f((u16)(wv >> 16)); ssum += f * f;
    wv = v.z; f = bf2f((u16)(wv & 0xffff)); ssum += f * f; f = bf2f((u16)(wv >> 16)); ssum += f * f;
    wv = v.w; f = bf2f((u16)(wv & 0xffff)); ssum += f * f; f = bf2f((u16)(wv >> 16)); ssum += f * f;
  }
#pragma unroll
  for (int m = 1; m < 64; m <<= 1) ssum += __shfl_xor(ssum, m);
  const float mean_base = ssum * (1.0f / (float)HD);

  // ---- a vectors (f32 from aV) ----
  const float* arow = aV + (size_t)n * 32;
  float a_tv[16], a_sv[16];
#pragma unroll
  for (int r = 0; r < 16; ++r) {
    a_tv[r] = arow[r];
    a_sv[r] = arow[16 + r];
  }

  // ---- cross + quad partials: lane handles expert e = lane&7, rows {2p,2p+1} ----
  const int e = lane & 7;
  const int pp = lane >> 3;
  const float* Ps = proj + (size_t)n * 256 + e * 16;
  const float* Pt = Ps + 128;
  const float* Gss = grams + e * 256;
  const float* Gst = grams + 2048 + e * 256;
  const float* Gtt = grams + 4096 + e * 256;
  float crossp = 0.f, qss = 0.f, qst = 0.f, qtt = 0.f;
#pragma unroll
  for (int rr = 0; rr < 2; ++rr) {
    int r = pp * 2 + rr;
    float asr = arow[16 + r];
    float atr = arow[r];
    crossp += 2.0f * Ps[r] * asr - 2.0f * Pt[r] * atr;   // SCALE_S = SCALE_T = 2
    const float* gssr = Gss + r * 16;
    const float* gstr = Gst + r * 16;
    const float* gttr = Gtt + r * 16;
    float vss = 0.f, vst = 0.f, vtt = 0.f;
#pragma unroll
    for (int q = 0; q < 16; ++q) {
      vss += gssr[q] * a_sv[q];
      vst += gstr[q] * a_tv[q];
      vtt += gttr[q] * a_tv[q];
    }
    qss += asr * vss;
    qst += asr * vst;
    qtt += atr * vtt;
  }
#pragma unroll
  for (int m = 8; m < 64; m <<= 1) {
    crossp += __shfl_xor(crossp, m);
    qss += __shfl_xor(qss, m);
    qst += __shfl_xor(qst, m);
    qtt += __shfl_xor(qtt, m);
  }
  float quad = 4.0f * qss - 8.0f * qst + 4.0f * qtt;
  float my_mse = mean_base + (2.0f / (float)HD) * crossp + (1.0f / (float)HD) * quad;

  // ---- method A: K=3 MC scan with alpha-renorm ----
  float p[8], gt[8], gs[8];
#pragma unroll
  for (int i = 0; i < 8; ++i) {
    gt[i] = tg[(size_t)n * 8 + i];
    gs[i] = sg[(size_t)n * 8 + i];
    p[i] = gt[i];
  }
  const float mf = (float)maskp[n];
  float feat = 0.f, wsum = 0.f;
  float tc[8] = {0, 0, 0, 0, 0, 0, 0, 0};
  float sc[8] = {0, 0, 0, 0, 0, 0, 0, 0};
#pragma unroll
  for (int k = 0; k < 3; ++k) {
    int idx = 0;
    float best = -1e30f;
#pragma unroll
    for (int i = 0; i < 8; ++i) {
      float u = un[((size_t)k * NTOK + n) * 8 + i];
      float g = -logf(-logf(u * (1.0f - 2e-7f) + 1e-7f));
      float s = logf(p[i]) + g;
      if (s > best) { best = s; idx = i; }
    }
    float wgt = 0.f, sgi = 0.f;
#pragma unroll
    for (int i = 0; i < 8; ++i)
      if (i == idx) { wgt = p[i]; sgi = gs[i]; }
    float mse_k = __shfl(my_mse, idx);
    feat += mf * wgt * mse_k;
    wsum += mf * wgt;
#pragma unroll
    for (int i = 0; i < 8; ++i)
      if (i == idx) { tc[i] += mf * wgt; sc[i] += mf * sgi; }
    float sum = 0.f;
#pragma unroll
    for (int i = 0; i < 8; ++i) {
      if (i == idx) p[i] *= 0.5f;   // ALPHA = 0.5
      sum += p[i];
    }
#pragma unroll
    for (int i = 0; i < 8; ++i) p[i] /= sum;
  }

  // ---- method B ----
  float tcl = fminf(fmaxf(temp[0], 0.5f), 1.5f);
  float invt = 1.0f / tcl;
  float x[8];
  float xm = -1e30f;
#pragma unroll
  for (int i = 0; i < 8; ++i) { x[i] = gs[i] * invt; xm = fmaxf(xm, x[i]); }
  float sx = 0.f;
#pragma unroll
  for (int i = 0; i < 8; ++i) sx += expf(x[i] - xm);
  float lse = xm + logf(sx);
  float tkl = 0.f, ent = 0.f;
#pragma unroll
  for (int i = 0; i < 8; ++i) {
    tkl += gt[i] * (logf(gt[i]) - (x[i] - lse));
    ent -= gs[i] * logf(gs[i]);
  }

  if (lane == 0) {
    atomicAdd(&blk[0], feat);
    atomicAdd(&blk[1], wsum);
#pragma unroll
    for (int i = 0; i < 8; ++i) {
      atomicAdd(&blk[2 + i], tc[i]);
      atomicAdd(&blk[10 + i], sc[i]);
    }
    atomicAdd(&blk[18], tkl);
    atomicAdd(&blk[19], ent);
  }
  __syncthreads();
  if (threadIdx.x < 20) atomicAdd(&accum[threadIdx.x], blk[threadIdx.x]);
}

// ---------------- finalize ----------------
__global__ void finalize_k(const float* __restrict__ accum, const float* __restrict__ temp,
                           float* __restrict__ out) {
  if (threadIdx.x != 0 || blockIdx.x != 0) return;
  float feat = accum[0] / fmaxf(accum[1], 1e-8f);
  float tsum = 0.f, ssum = 0.f;
  for (int e2 = 0; e2 < 8; ++e2) { tsum += accum[2 + e2]; ssum += accum[10 + e2]; }
  float ta[8], sa[8];
  float tas = 0.f, sas = 0.f;
  for (int e2 = 0; e2 < 8; ++e2) {
    ta[e2] = accum[2 + e2] / tsum + 1e-8f; tas += ta[e2];
    sa[e2] = accum[10 + e2] / ssum + 1e-8f; sas += sa[e2];
  }
  float cov = 0.f;
  for (int e2 = 0; e2 < 8; ++e2) {
    float tt = ta[e2] / tas, sv = sa[e2] / sas;
    cov += tt * (logf(tt) - logf(sv));
  }
  cov /= 8.0f;
  float tcl = fminf(fmaxf(temp[0], 0.5f), 1.5f);
  float tkl = accum[18] / 8.0f;
  float entl = -accum[19] / (float)NTOK;
  out[0] = feat;
  out[1] = cov;
  out[2] = feat + 0.5f * cov;
  out[3] = tkl;
  out[4] = entl;
  out[5] = tkl + 0.1f * entl;
  out[6] = tcl;
}

// ---------------- launch ----------------
extern "C" void kernel_launch(void* const* d_in, const int* in_sizes, int n_in,
                              void* d_out, int out_size, void* d_ws, size_t ws_size,
                              hipStream_t stream) {
  const float* tg = (const float*)d_in[0];
  const float* sg = (const float*)d_in[1];
  const float* th = (const float*)d_in[2];
  const float* sh = (const float*)d_in[3];
  const int* mask = (const int*)d_in[4];
  const float* un = (const float*)d_in[5];
  const float* W_t = (const float*)d_in[6];
  const float* b_t = (const float*)d_in[7];
  const float* A_t = (const float*)d_in[8];
  const float* B_t = (const float*)d_in[9];
  const float* W_s = (const float*)d_in[10];
  const float* b_s = (const float*)d_in[11];
  const float* A_s = (const float*)d_in[12];
  const float* B_s = (const float*)d_in[13];
  const float* temp = (const float*)d_in[14];
  float* out = (float*)d_out;

  char* ws = (char*)d_ws;
  const size_t OFF_X = 0;                                  // 134217728
  const size_t OFF_W = OFF_X + (size_t)NTOK * KX * 2;      // Wc 16777216
  const size_t OFF_WA = OFF_W + (size_t)HD * KX * 2;       // WcA 1048576
  const size_t OFF_D = OFF_WA + (size_t)128 * KX * 2;      // D 67108864
  const size_t OFF_BC = OFF_D + (size_t)NTOK * HD * 2;     // Bc 1048576
  const size_t OFF_PJ = OFF_BC + (size_t)256 * HD * 2;     // proj 16777216
  const size_t OFF_AV = OFF_PJ + (size_t)NTOK * 256 * 4;   // aV 2097152
  const size_t OFF_GR = OFF_AV + (size_t)NTOK * 32 * 4;    // grams 24576
  const size_t OFF_AC = OFF_GR + 6144 * 4;                 // accum 128
  const size_t OFF_BI = OFF_AC + 128;                      // dbias 8192

  u16* X = (u16*)(ws + OFF_X);
  u16* Wc = (u16*)(ws + OFF_W);
  u16* WcA = (u16*)(ws + OFF_WA);
  u16* D = (u16*)(ws + OFF_D);
  u16* Bc = (u16*)(ws + OFF_BC);
  float* proj = (float*)(ws + OFF_PJ);
  float* aV = (float*)(ws + OFF_AV);
  float* grams = (float*)(ws + OFF_GR);
  float* accum = (float*)(ws + OFF_AC);
  float* dbias = (float*)(ws + OFF_BI);

  zero_k<<<25, 256, 0, stream>>>(grams, 6176);   // grams + accum (contiguous)
  make_bias_k<<<8, 256, 0, stream>>>(b_t, b_s, dbias);
  convert_X_k<<<32768, 256, 0, stream>>>(th, sh, X);
  convert_W_k<<<4352, 256, 0, stream>>>(W_t, W_s, A_t, A_s, Wc, WcA);
  convert_Bc_k<<<256, 256, 0, stream>>>(B_s, B_t, Bc);
  gram_k<<<128, 256, 0, stream>>>(B_s, B_t, grams);

  // d = X @ Wc^T + dbias, bf16 [16384][2048]
  gemm256_k<<<512, 512, 0, stream>>>(X, Wc, D, dbias);
  // aV = X @ WcA^T (cols 0..31), f32 [16384][32]
  gemm_bt_k<<<dim3(128, 1), 256, 0, stream>>>(X, KX, WcA, KX, KX, aV, 32, 32);
  // proj = d @ Bc^T, f32 [16384][256]
  gemm_bt_k<<<dim3(128, 2), 256, 0, stream>>>(D, HD, Bc, HD, HD, proj, 256, 256);

  token_k<<<4096, 256, 0, stream>>>(D, aV, proj, grams, tg, sg, un, mask, temp, accum);
  finalize_k<<<1, 64, 0, stream>>>(accum, temp, out);
}